// Round 26
// baseline (39.353 us; speedup 1.0000x reference)
//
#include <hip/hip_runtime.h>

namespace {
constexpr int Wd = 160, Hd = 192, Dd = 160, Bd = 2;
constexpr int HW = Hd * Wd;
constexpr int THREADS = 256;               // 4 waves
constexpr int ROWS_OUT = 6;                // output rows per block
constexpr int ROWS_LDS = 8;                // staged rows incl. h-halo
constexpr int RS = 164;                    // fp16 row stride (halves)
constexpr int STRIPS = 40;                 // 4-wide strips per row
constexpr int CTHREADS = ROWS_OUT * STRIPS;   // 240 compute threads
constexpr int TASKS = 2 * ROWS_LDS * STRIPS;  // 640 staging tasks
constexpr int DCHUNK = 8;                  // grid 1280 = 5 blocks/CU, 20 waves/CU
constexpr int NCHUNK = Dd / DCHUNK;        // 20
constexpr int RGROUPS = Hd / ROWS_OUT;     // 32
constexpr float EPS = 1e-8f;
}

using v4f = __attribute__((ext_vector_type(4))) float;
using v4h = __attribute__((ext_vector_type(4))) _Float16;

__device__ __forceinline__ float dpp_up1(float v) {   // lane i <- lane i-1
  return __int_as_float(__builtin_amdgcn_update_dpp(
      0, __float_as_int(v), 0x138, 0xF, 0xF, true));  // wave_shr:1
}
__device__ __forceinline__ float dpp_dn1(float v) {   // lane i <- lane i+1
  return __int_as_float(__builtin_amdgcn_update_dpp(
      0, __float_as_int(v), 0x130, 0xF, 0xF, true));  // wave_shl:1
}

__global__ __launch_bounds__(THREADS) void sobel_loss_kernel(
    const float* __restrict__ pred, const float* __restrict__ targ,
    float* __restrict__ out) {
  // staged separable row partials in fp16: sw = [1,2,1]_w*x, dw = [-1,0,1]_w*x
  __shared__ __align__(16) _Float16 lsw[2][ROWS_LDS][RS];   // 5.2 KB
  __shared__ __align__(16) _Float16 ldw[2][ROWS_LDS][RS];   // 5.2 KB
  const int tid = threadIdx.x;
  const int lane = tid & 63;
  const int h0 = blockIdx.x * ROWS_OUT;
  const int d0 = blockIdx.y * DCHUNK;
  const size_t volOff = (size_t)blockIdx.z * Dd * HW;
  const float* pb = pred + volOff;
  const float* tb = targ + volOff;

  // ---- staging task decode (2.5 tasks/thread, loop-invariant) ----
  const float* gs[3];
  _Float16* psw[3];
  _Float16* pdw[3];
  bool sok[3], rok[3], zL[3], zR[3], pL[3], pR[3];
#pragma unroll
  for (int u = 0; u < 3; ++u) {
    const int i = tid + 256 * u;
    const bool ok = (i < TASKS);
    const int ic = ok ? i : 0;
    const int t_ = ic / (ROWS_LDS * STRIPS);
    const int rem = ic - t_ * (ROWS_LDS * STRIPS);
    const int r8 = rem / STRIPS, s = rem - r8 * STRIPS;
    const int hh = h0 - 1 + r8;
    const bool rv = ok && ((unsigned)hh < (unsigned)Hd);
    sok[u] = ok;
    rok[u] = rv;
    zL[u] = (s == 0);
    zR[u] = (s == STRIPS - 1);
    pL[u] = ok && (lane == 0) && (s != 0);
    pR[u] = ok && (lane == 63) && (s != STRIPS - 1);
    gs[u] = (t_ ? tb : pb) + (size_t)(rv ? hh : 0) * Wd + s * 4;
    psw[u] = &lsw[t_][r8][s * 4];
    pdw[u] = &ldw[t_][r8][s * 4];
  }

  float4 m[3];
  float hl[3], hr[3];
  auto GLOAD = [&](int d) {   // float4-only + <=2 exec-masked scalars per wave
    const bool dok = (unsigned)d < (unsigned)Dd;
    const size_t so = (size_t)d * HW;
#pragma unroll
    for (int u = 0; u < 3; ++u) {
      float4 v = make_float4(0.f, 0.f, 0.f, 0.f);
      float a = 0.f, b = 0.f;
      if (dok && rok[u]) {
        v = *reinterpret_cast<const float4*>(gs[u] + so);
        if (pL[u]) a = gs[u][so - 1];
        if (pR[u]) b = gs[u][so + 4];
      }
      m[u] = v; hl[u] = a; hr[u] = b;
    }
  };

  auto STAGE = [&]() {   // w-conv in f32, convert, write fp16 sw/dw (b64)
#pragma unroll
    for (int u = 0; u < 3; ++u) {
      float xl = dpp_up1(m[u].w);          // lane-1 holds x[4s-4..4s-1]
      float xr = dpp_dn1(m[u].x);          // lane+1 holds x[4s+4..4s+7]
      if (zL[u]) xl = 0.f;
      if (pL[u]) xl = hl[u];
      if (zR[u]) xr = 0.f;
      if (pR[u]) xr = hr[u];
      const float x0 = xl, x1 = m[u].x, x2 = m[u].y, x3 = m[u].z,
                  x4 = m[u].w, x5 = xr;
      v4f swf, dwf;
      swf[0] = fmaf(2.f, x1, x0 + x2);  dwf[0] = x2 - x0;
      swf[1] = fmaf(2.f, x2, x1 + x3);  dwf[1] = x3 - x1;
      swf[2] = fmaf(2.f, x3, x2 + x4);  dwf[2] = x4 - x2;
      swf[3] = fmaf(2.f, x4, x3 + x5);  dwf[3] = x5 - x3;
      if (sok[u]) {
        *reinterpret_cast<v4h*>(psw[u]) = __builtin_convertvector(swf, v4h);
        *reinterpret_cast<v4h*>(pdw[u]) = __builtin_convertvector(dwf, v4h);
      }
    }
  };

  // ---- compute decode: output row cr (0..5), strip cs (0..39) ----
  const int cr = tid / STRIPS;
  const int cs4 = (tid - cr * STRIPS) * 4;
  const bool is_c = (tid < CTHREADS);

  // rolling state [slot][tensor] as packed fp16 -> v_pk_*_f16 math
  v4h A[3][2], B[3][2], C[3][2];
  const _Float16 h2 = (_Float16)2.0f;

  auto HCONV = [&](int slot) {
#pragma unroll
    for (int t_ = 0; t_ < 2; ++t_) {
      const v4h sm = *reinterpret_cast<const v4h*>(&lsw[t_][cr][cs4]);
      const v4h s0 = *reinterpret_cast<const v4h*>(&lsw[t_][cr + 1][cs4]);
      const v4h sp = *reinterpret_cast<const v4h*>(&lsw[t_][cr + 2][cs4]);
      const v4h dm = *reinterpret_cast<const v4h*>(&ldw[t_][cr][cs4]);
      const v4h dd = *reinterpret_cast<const v4h*>(&ldw[t_][cr + 1][cs4]);
      const v4h dp = *reinterpret_cast<const v4h*>(&ldw[t_][cr + 2][cs4]);
      A[slot][t_] = s0 * h2 + (sm + sp);
      B[slot][t_] = dd * h2 + (dm + dp);
      C[slot][t_] = sp - sm;
    }
  };

  v4f accv = {0.f, 0.f, 0.f, 0.f};

  // ---- prologue: slices d0-1 (slot0) and d0 (slot1) ----
  GLOAD(d0 - 1);
  STAGE(); GLOAD(d0); __syncthreads();
  if (is_c) HCONV(0);
  __syncthreads();
  STAGE(); GLOAD(d0 + 1); __syncthreads();
  if (is_c) HCONV(1);
  __syncthreads();

  // ---- main loop, fully unrolled: output slice d0+k ----
#pragma unroll
  for (int k = 0; k < DCHUNK; ++k) {
    STAGE();                               // LDS <- slice d0+1+k (loaded last iter)
    if (k < DCHUNK - 1) GLOAD(d0 + 2 + k); // issue next; consumed next iter top
    __syncthreads();
    const int i0 = k % 3, i1 = (k + 1) % 3, i2 = (k + 2) % 3;
    if (is_c) {
      HCONV(i2);                           // state <- slice d0+1+k
      const v4h gx0 = B[i1][0] * h2 + (B[i0][0] + B[i2][0]);
      const v4h gy0 = C[i1][0] * h2 + (C[i0][0] + C[i2][0]);
      const v4h gz0 = A[i2][0] - A[i0][0];
      const v4h q0h = gx0 * gx0 + gy0 * gy0 + gz0 * gz0;
      const v4h gx1 = B[i1][1] * h2 + (B[i0][1] + B[i2][1]);
      const v4h gy1 = C[i1][1] * h2 + (C[i0][1] + C[i2][1]);
      const v4h gz1 = A[i2][1] - A[i0][1];
      const v4h q1h = gx1 * gx1 + gy1 * gy1 + gz1 * gz1;
      const v4f q0 = __builtin_convertvector(q0h, v4f) + EPS;
      const v4f q1 = __builtin_convertvector(q1h, v4f) + EPS;
      v4f dd_;
#pragma unroll
      for (int j = 0; j < 4; ++j)
        dd_[j] = __builtin_amdgcn_sqrtf(q0[j]) - __builtin_amdgcn_sqrtf(q1[j]);
#pragma unroll
      for (int j = 0; j < 4; ++j) dd_[j] = fabsf(dd_[j]);
      accv += dd_;
    }
    __syncthreads();
  }

  // ---- reduction: wave shfl -> LDS -> one atomic per block ----
  float sred = accv[0] + accv[1] + accv[2] + accv[3];
#pragma unroll
  for (int off = 32; off > 0; off >>= 1) sred += __shfl_down(sred, off, 64);
  __shared__ float wsum[THREADS / 64];
  const int wid = tid >> 6;
  if (lane == 0) wsum[wid] = sred;
  __syncthreads();
  if (tid == 0) {
    float t = 0.f;
#pragma unroll
    for (int i = 0; i < THREADS / 64; ++i) t += wsum[i];
    atomicAdd(out, t * (1.0f / (float)((size_t)Bd * Dd * Hd * Wd)));
  }
}

extern "C" void kernel_launch(void* const* d_in, const int* in_sizes, int n_in,
                              void* d_out, int out_size, void* d_ws, size_t ws_size,
                              hipStream_t stream) {
  const float* pred = (const float*)d_in[0];
  const float* targ = (const float*)d_in[1];
  float* out = (float*)d_out;
  (void)in_sizes; (void)n_in; (void)out_size; (void)d_ws; (void)ws_size;

  hipMemsetAsync(out, 0, sizeof(float), stream);
  dim3 grid(RGROUPS, NCHUNK, Bd);
  sobel_loss_kernel<<<grid, THREADS, 0, stream>>>(pred, targ, out);
}

// Round 27
// 36.520 us; speedup vs baseline: 1.0776x; 1.0776x over previous
//
#include <hip/hip_runtime.h>

namespace {
constexpr int Wd = 160, Hd = 192, Dd = 160, Bd = 2;
constexpr int HW = Hd * Wd;
constexpr int THREADS = 256;               // 4 waves
constexpr int ROWS_OUT = 6;                // output rows per block
constexpr int ROWS_LDS = 8;                // staged rows incl. h-halo
constexpr int RS8 = 41 * 8;                // halves per row: 40 groups + 1 pad (656 B)
constexpr int STRIPS = 40;                 // 4-wide strips per row
constexpr int CTHREADS = ROWS_OUT * STRIPS;   // 240 compute threads
constexpr int TASKS = 2 * ROWS_LDS * STRIPS;  // 640 staging tasks
constexpr int DCHUNK = 10;                 // grid 1024 (proven best)
constexpr int NCHUNK = Dd / DCHUNK;        // 16
constexpr int RGROUPS = Hd / ROWS_OUT;     // 32
constexpr float EPS = 1e-8f;
}

using v4f = __attribute__((ext_vector_type(4))) float;
using v4h = __attribute__((ext_vector_type(4))) _Float16;
using v8h = __attribute__((ext_vector_type(8))) _Float16;

__device__ __forceinline__ float dpp_up1(float v) {   // lane i <- lane i-1
  return __int_as_float(__builtin_amdgcn_update_dpp(
      0, __float_as_int(v), 0x138, 0xF, 0xF, true));  // wave_shr:1
}
__device__ __forceinline__ float dpp_dn1(float v) {   // lane i <- lane i+1
  return __int_as_float(__builtin_amdgcn_update_dpp(
      0, __float_as_int(v), 0x130, 0xF, 0xF, true));  // wave_shl:1
}

__global__ __launch_bounds__(THREADS) void sobel_loss_kernel(
    const float* __restrict__ pred, const float* __restrict__ targ,
    float* __restrict__ out) {
  // interleaved fp16 row partials: group s of row r = {sw0..3, dw0..3} (16 B)
  // -> STAGE: 1 b128 write/task; HCONV: 3 b128 reads/tensor (was 2+6 b64)
  __shared__ __align__(16) _Float16 lds[2][ROWS_LDS][RS8];   // 10.5 KB
  const int tid = threadIdx.x;
  const int lane = tid & 63;
  const int h0 = blockIdx.x * ROWS_OUT;
  const int d0 = blockIdx.y * DCHUNK;
  const size_t volOff = (size_t)blockIdx.z * Dd * HW;
  const float* pb = pred + volOff;
  const float* tb = targ + volOff;

  // ---- staging task decode (2.5 tasks/thread, loop-invariant) ----
  const float* gs[3];
  _Float16* pgr[3];
  bool sok[3], rok[3], zL[3], zR[3], pL[3], pR[3];
#pragma unroll
  for (int u = 0; u < 3; ++u) {
    const int i = tid + 256 * u;
    const bool ok = (i < TASKS);
    const int ic = ok ? i : 0;
    const int t_ = ic / (ROWS_LDS * STRIPS);
    const int rem = ic - t_ * (ROWS_LDS * STRIPS);
    const int r8 = rem / STRIPS, s = rem - r8 * STRIPS;
    const int hh = h0 - 1 + r8;
    const bool rv = ok && ((unsigned)hh < (unsigned)Hd);
    sok[u] = ok;
    rok[u] = rv;
    zL[u] = (s == 0);
    zR[u] = (s == STRIPS - 1);
    pL[u] = ok && (lane == 0) && (s != 0);
    pR[u] = ok && (lane == 63) && (s != STRIPS - 1);
    gs[u] = (t_ ? tb : pb) + (size_t)(rv ? hh : 0) * Wd + s * 4;
    pgr[u] = &lds[t_][r8][s * 8];
  }

  float4 m[3];
  float hl[3], hr[3];
  auto GLOAD = [&](int d) {   // float4-only + <=2 exec-masked scalars per wave
    const bool dok = (unsigned)d < (unsigned)Dd;
    const size_t so = (size_t)d * HW;
#pragma unroll
    for (int u = 0; u < 3; ++u) {
      float4 v = make_float4(0.f, 0.f, 0.f, 0.f);
      float a = 0.f, b = 0.f;
      if (dok && rok[u]) {
        v = *reinterpret_cast<const float4*>(gs[u] + so);
        if (pL[u]) a = gs[u][so - 1];
        if (pR[u]) b = gs[u][so + 4];
      }
      m[u] = v; hl[u] = a; hr[u] = b;
    }
  };

  auto STAGE = [&]() {   // w-conv in f32, convert, ONE b128 write per task
#pragma unroll
    for (int u = 0; u < 3; ++u) {
      float xl = dpp_up1(m[u].w);          // lane-1 holds x[4s-4..4s-1]
      float xr = dpp_dn1(m[u].x);          // lane+1 holds x[4s+4..4s+7]
      if (zL[u]) xl = 0.f;
      if (pL[u]) xl = hl[u];
      if (zR[u]) xr = 0.f;
      if (pR[u]) xr = hr[u];
      const float x0 = xl, x1 = m[u].x, x2 = m[u].y, x3 = m[u].z,
                  x4 = m[u].w, x5 = xr;
      v4f swf, dwf;
      swf[0] = fmaf(2.f, x1, x0 + x2);  dwf[0] = x2 - x0;
      swf[1] = fmaf(2.f, x2, x1 + x3);  dwf[1] = x3 - x1;
      swf[2] = fmaf(2.f, x3, x2 + x4);  dwf[2] = x4 - x2;
      swf[3] = fmaf(2.f, x4, x3 + x5);  dwf[3] = x5 - x3;
      if (sok[u]) {
        const v4h swh = __builtin_convertvector(swf, v4h);
        const v4h dwh = __builtin_convertvector(dwf, v4h);
        *reinterpret_cast<v8h*>(pgr[u]) =
            __builtin_shufflevector(swh, dwh, 0, 1, 2, 3, 4, 5, 6, 7);
      }
    }
  };

  // ---- compute decode: output row cr (0..5), strip cs (0..39) ----
  const int cr = tid / STRIPS;
  const int cs8 = (tid - cr * STRIPS) * 8;
  const bool is_c = (tid < CTHREADS);

  // rolling state [slot][tensor] as packed fp16 -> v_pk_*_f16 math
  v4h A[3][2], B[3][2], C[3][2];
  const _Float16 h2 = (_Float16)2.0f;

  auto HCONV = [&](int slot) {   // 3 b128 reads per tensor; unpack is free
#pragma unroll
    for (int t_ = 0; t_ < 2; ++t_) {
      const v8h r0 = *reinterpret_cast<const v8h*>(&lds[t_][cr][cs8]);
      const v8h r1 = *reinterpret_cast<const v8h*>(&lds[t_][cr + 1][cs8]);
      const v8h r2 = *reinterpret_cast<const v8h*>(&lds[t_][cr + 2][cs8]);
      const v4h sm = __builtin_shufflevector(r0, r0, 0, 1, 2, 3);
      const v4h dm = __builtin_shufflevector(r0, r0, 4, 5, 6, 7);
      const v4h s0 = __builtin_shufflevector(r1, r1, 0, 1, 2, 3);
      const v4h dd = __builtin_shufflevector(r1, r1, 4, 5, 6, 7);
      const v4h sp = __builtin_shufflevector(r2, r2, 0, 1, 2, 3);
      const v4h dp = __builtin_shufflevector(r2, r2, 4, 5, 6, 7);
      A[slot][t_] = s0 * h2 + (sm + sp);
      B[slot][t_] = dd * h2 + (dm + dp);
      C[slot][t_] = sp - sm;
    }
  };

  v4f accv = {0.f, 0.f, 0.f, 0.f};

  // ---- prologue: slices d0-1 (slot0) and d0 (slot1) ----
  GLOAD(d0 - 1);
  STAGE(); GLOAD(d0); __syncthreads();
  if (is_c) HCONV(0);
  __syncthreads();
  STAGE(); GLOAD(d0 + 1); __syncthreads();
  if (is_c) HCONV(1);
  __syncthreads();

  // ---- main loop, fully unrolled: output slice d0+k ----
#pragma unroll
  for (int k = 0; k < DCHUNK; ++k) {
    STAGE();                               // LDS <- slice d0+1+k (loaded last iter)
    if (k < DCHUNK - 1) GLOAD(d0 + 2 + k); // issue next; consumed next iter top
    __syncthreads();
    const int i0 = k % 3, i1 = (k + 1) % 3, i2 = (k + 2) % 3;
    if (is_c) {
      HCONV(i2);                           // state <- slice d0+1+k
      const v4h gx0 = B[i1][0] * h2 + (B[i0][0] + B[i2][0]);
      const v4h gy0 = C[i1][0] * h2 + (C[i0][0] + C[i2][0]);
      const v4h gz0 = A[i2][0] - A[i0][0];
      const v4h q0h = gx0 * gx0 + gy0 * gy0 + gz0 * gz0;
      const v4h gx1 = B[i1][1] * h2 + (B[i0][1] + B[i2][1]);
      const v4h gy1 = C[i1][1] * h2 + (C[i0][1] + C[i2][1]);
      const v4h gz1 = A[i2][1] - A[i0][1];
      const v4h q1h = gx1 * gx1 + gy1 * gy1 + gz1 * gz1;
      const v4f q0 = __builtin_convertvector(q0h, v4f) + EPS;
      const v4f q1 = __builtin_convertvector(q1h, v4f) + EPS;
      v4f dd_;
#pragma unroll
      for (int j = 0; j < 4; ++j)
        dd_[j] = __builtin_amdgcn_sqrtf(q0[j]) - __builtin_amdgcn_sqrtf(q1[j]);
#pragma unroll
      for (int j = 0; j < 4; ++j) dd_[j] = fabsf(dd_[j]);
      accv += dd_;
    }
    __syncthreads();
  }

  // ---- reduction: wave shfl -> LDS -> one atomic per block ----
  float sred = accv[0] + accv[1] + accv[2] + accv[3];
#pragma unroll
  for (int off = 32; off > 0; off >>= 1) sred += __shfl_down(sred, off, 64);
  __shared__ float wsum[THREADS / 64];
  const int wid = tid >> 6;
  if (lane == 0) wsum[wid] = sred;
  __syncthreads();
  if (tid == 0) {
    float t = 0.f;
#pragma unroll
    for (int i = 0; i < THREADS / 64; ++i) t += wsum[i];
    atomicAdd(out, t * (1.0f / (float)((size_t)Bd * Dd * Hd * Wd)));
  }
}

extern "C" void kernel_launch(void* const* d_in, const int* in_sizes, int n_in,
                              void* d_out, int out_size, void* d_ws, size_t ws_size,
                              hipStream_t stream) {
  const float* pred = (const float*)d_in[0];
  const float* targ = (const float*)d_in[1];
  float* out = (float*)d_out;
  (void)in_sizes; (void)n_in; (void)out_size; (void)d_ws; (void)ws_size;

  hipMemsetAsync(out, 0, sizeof(float), stream);
  dim3 grid(RGROUPS, NCHUNK, Bd);
  sobel_loss_kernel<<<grid, THREADS, 0, stream>>>(pred, targ, out);
}

// Round 28
// 33.824 us; speedup vs baseline: 1.1635x; 1.0797x over previous
//
#include <hip/hip_runtime.h>

namespace {
constexpr int Wd = 160, Hd = 192, Dd = 160, Bd = 2;
constexpr int HW = Hd * Wd;
constexpr int THREADS = 256;               // 4 waves
constexpr int ROWS_OUT = 12;               // output rows per block (2/thread)
constexpr int ROWS_LDS = 14;               // staged rows incl. h-halo
constexpr int RS = 164;                    // fp16 row stride (halves)
constexpr int STRIPS = 40;                 // 4-wide strips per row
constexpr int CTHREADS = 240;              // 6 row-pairs x 40 strips
constexpr int TASKS = 2 * ROWS_LDS * STRIPS;  // 1120 staging tasks
constexpr int NSLOT = 5;                   // ceil(1120/256)
constexpr int DCHUNK = 10;
constexpr int NCHUNK = Dd / DCHUNK;        // 16
constexpr int RGROUPS = Hd / ROWS_OUT;     // 16 -> grid 512 = 2 blocks/CU
constexpr float EPS = 1e-8f;
}

using v4f = __attribute__((ext_vector_type(4))) float;
using v4h = __attribute__((ext_vector_type(4))) _Float16;

__device__ __forceinline__ float dpp_up1(float v) {   // lane i <- lane i-1
  return __int_as_float(__builtin_amdgcn_update_dpp(
      0, __float_as_int(v), 0x138, 0xF, 0xF, true));  // wave_shr:1
}
__device__ __forceinline__ float dpp_dn1(float v) {   // lane i <- lane i+1
  return __int_as_float(__builtin_amdgcn_update_dpp(
      0, __float_as_int(v), 0x130, 0xF, 0xF, true));  // wave_shl:1
}

__global__ __launch_bounds__(THREADS) void sobel_loss_kernel(
    const float* __restrict__ pred, const float* __restrict__ targ,
    float* __restrict__ out) {
  // staged separable row partials in fp16: sw = [1,2,1]_w*x, dw = [-1,0,1]_w*x
  __shared__ __align__(16) _Float16 lsw[2][ROWS_LDS][RS];   // 9.0 KB
  __shared__ __align__(16) _Float16 ldw[2][ROWS_LDS][RS];   // 9.0 KB
  const int tid = threadIdx.x;
  const int lane = tid & 63;
  const int h0 = blockIdx.x * ROWS_OUT;
  const int d0 = blockIdx.y * DCHUNK;
  const size_t volOff = (size_t)blockIdx.z * Dd * HW;
  const float* pb = pred + volOff;
  const float* tb = targ + volOff;

  // ---- staging task decode (up to 5 tasks/thread, loop-invariant) ----
  const float* gs[NSLOT];
  _Float16* psw[NSLOT];
  _Float16* pdw[NSLOT];
  bool sok[NSLOT], rok[NSLOT], zL[NSLOT], zR[NSLOT], pL[NSLOT], pR[NSLOT];
#pragma unroll
  for (int u = 0; u < NSLOT; ++u) {
    const int i = tid + 256 * u;
    const bool ok = (i < TASKS);
    const int ic = ok ? i : 0;
    const int t_ = ic / (ROWS_LDS * STRIPS);
    const int rem = ic - t_ * (ROWS_LDS * STRIPS);
    const int r8 = rem / STRIPS, s = rem - r8 * STRIPS;
    const int hh = h0 - 1 + r8;
    const bool rv = ok && ((unsigned)hh < (unsigned)Hd);
    sok[u] = ok;
    rok[u] = rv;
    zL[u] = (s == 0);
    zR[u] = (s == STRIPS - 1);
    pL[u] = ok && (lane == 0) && (s != 0);
    pR[u] = ok && (lane == 63) && (s != STRIPS - 1);
    gs[u] = (t_ ? tb : pb) + (size_t)(rv ? hh : 0) * Wd + s * 4;
    psw[u] = &lsw[t_][r8][s * 4];
    pdw[u] = &ldw[t_][r8][s * 4];
  }

  float4 m[NSLOT];
  float hl[NSLOT], hr[NSLOT];
  auto GLOAD = [&](int d) {   // float4-only + exec-masked edge scalars
    const bool dok = (unsigned)d < (unsigned)Dd;
    const size_t so = (size_t)d * HW;
#pragma unroll
    for (int u = 0; u < NSLOT; ++u) {
      float4 v = make_float4(0.f, 0.f, 0.f, 0.f);
      float a = 0.f, b = 0.f;
      if (dok && rok[u]) {
        v = *reinterpret_cast<const float4*>(gs[u] + so);
        if (pL[u]) a = gs[u][so - 1];
        if (pR[u]) b = gs[u][so + 4];
      }
      m[u] = v; hl[u] = a; hr[u] = b;
    }
  };

  auto STAGE = [&]() {   // w-conv in f32, convert, write fp16 sw/dw (b64)
#pragma unroll
    for (int u = 0; u < NSLOT; ++u) {
      float xl = dpp_up1(m[u].w);          // lane-1 holds x[4s-4..4s-1]
      float xr = dpp_dn1(m[u].x);          // lane+1 holds x[4s+4..4s+7]
      if (zL[u]) xl = 0.f;
      if (pL[u]) xl = hl[u];
      if (zR[u]) xr = 0.f;
      if (pR[u]) xr = hr[u];
      const float x0 = xl, x1 = m[u].x, x2 = m[u].y, x3 = m[u].z,
                  x4 = m[u].w, x5 = xr;
      v4f swf, dwf;
      swf[0] = fmaf(2.f, x1, x0 + x2);  dwf[0] = x2 - x0;
      swf[1] = fmaf(2.f, x2, x1 + x3);  dwf[1] = x3 - x1;
      swf[2] = fmaf(2.f, x3, x2 + x4);  dwf[2] = x4 - x2;
      swf[3] = fmaf(2.f, x4, x3 + x5);  dwf[3] = x5 - x3;
      if (sok[u]) {
        *reinterpret_cast<v4h*>(psw[u]) = __builtin_convertvector(swf, v4h);
        *reinterpret_cast<v4h*>(pdw[u]) = __builtin_convertvector(dwf, v4h);
      }
    }
  };

  // ---- compute decode: rows cr and cr+6 (two independent chains), strip cs
  const int cr = tid / STRIPS;             // 0..5 for tid<240
  const int cs4 = (tid - cr * STRIPS) * 4;
  const bool is_c = (tid < CTHREADS);

  // rolling state [slot][tensor][half] as packed fp16 -> v_pk_*_f16 math
  v4h A[3][2][2], B[3][2][2], C[3][2][2];
  const _Float16 h2 = (_Float16)2.0f;

  auto HCONV = [&](int slot) {
#pragma unroll
    for (int hf = 0; hf < 2; ++hf) {
      const int r = cr + hf * 6;           // output rows cr, cr+6
#pragma unroll
      for (int t_ = 0; t_ < 2; ++t_) {
        const v4h sm = *reinterpret_cast<const v4h*>(&lsw[t_][r][cs4]);
        const v4h s0 = *reinterpret_cast<const v4h*>(&lsw[t_][r + 1][cs4]);
        const v4h sp = *reinterpret_cast<const v4h*>(&lsw[t_][r + 2][cs4]);
        const v4h dm = *reinterpret_cast<const v4h*>(&ldw[t_][r][cs4]);
        const v4h dd = *reinterpret_cast<const v4h*>(&ldw[t_][r + 1][cs4]);
        const v4h dp = *reinterpret_cast<const v4h*>(&ldw[t_][r + 2][cs4]);
        A[slot][t_][hf] = s0 * h2 + (sm + sp);
        B[slot][t_][hf] = dd * h2 + (dm + dp);
        C[slot][t_][hf] = sp - sm;
      }
    }
  };

  v4f accv = {0.f, 0.f, 0.f, 0.f};

  auto EMITF = [&](int i0, int i1, int i2) {
#pragma unroll
    for (int hf = 0; hf < 2; ++hf) {
      const v4h gx0 = B[i1][0][hf] * h2 + (B[i0][0][hf] + B[i2][0][hf]);
      const v4h gy0 = C[i1][0][hf] * h2 + (C[i0][0][hf] + C[i2][0][hf]);
      const v4h gz0 = A[i2][0][hf] - A[i0][0][hf];
      const v4h q0h = gx0 * gx0 + gy0 * gy0 + gz0 * gz0;
      const v4h gx1 = B[i1][1][hf] * h2 + (B[i0][1][hf] + B[i2][1][hf]);
      const v4h gy1 = C[i1][1][hf] * h2 + (C[i0][1][hf] + C[i2][1][hf]);
      const v4h gz1 = A[i2][1][hf] - A[i0][1][hf];
      const v4h q1h = gx1 * gx1 + gy1 * gy1 + gz1 * gz1;
      const v4f q0 = __builtin_convertvector(q0h, v4f) + EPS;
      const v4f q1 = __builtin_convertvector(q1h, v4f) + EPS;
      v4f dd_;
#pragma unroll
      for (int j = 0; j < 4; ++j)
        dd_[j] = __builtin_amdgcn_sqrtf(q0[j]) - __builtin_amdgcn_sqrtf(q1[j]);
#pragma unroll
      for (int j = 0; j < 4; ++j) dd_[j] = fabsf(dd_[j]);
      accv += dd_;
    }
  };

  // ---- prologue: slices d0-1 (slot0) and d0 (slot1) ----
  GLOAD(d0 - 1);
  STAGE(); GLOAD(d0); __syncthreads();
  if (is_c) HCONV(0);
  __syncthreads();
  STAGE(); GLOAD(d0 + 1); __syncthreads();
  if (is_c) HCONV(1);
  __syncthreads();

  // ---- main loop, fully unrolled: output slice d0+k ----
#pragma unroll
  for (int k = 0; k < DCHUNK; ++k) {
    STAGE();                               // LDS <- slice d0+1+k (loaded last iter)
    if (k < DCHUNK - 1) GLOAD(d0 + 2 + k); // issue next; consumed next iter top
    __syncthreads();
    const int i0 = k % 3, i1 = (k + 1) % 3, i2 = (k + 2) % 3;
    if (is_c) {
      HCONV(i2);                           // state <- slice d0+1+k
      EMITF(i0, i1, i2);                   // emit both rows (2x independent ILP)
    }
    __syncthreads();
  }

  // ---- reduction: wave shfl -> LDS -> one atomic per block ----
  float sred = accv[0] + accv[1] + accv[2] + accv[3];
#pragma unroll
  for (int off = 32; off > 0; off >>= 1) sred += __shfl_down(sred, off, 64);
  __shared__ float wsum[THREADS / 64];
  const int wid = tid >> 6;
  if (lane == 0) wsum[wid] = sred;
  __syncthreads();
  if (tid == 0) {
    float t = 0.f;
#pragma unroll
    for (int i = 0; i < THREADS / 64; ++i) t += wsum[i];
    atomicAdd(out, t * (1.0f / (float)((size_t)Bd * Dd * Hd * Wd)));
  }
}

extern "C" void kernel_launch(void* const* d_in, const int* in_sizes, int n_in,
                              void* d_out, int out_size, void* d_ws, size_t ws_size,
                              hipStream_t stream) {
  const float* pred = (const float*)d_in[0];
  const float* targ = (const float*)d_in[1];
  float* out = (float*)d_out;
  (void)in_sizes; (void)n_in; (void)out_size; (void)d_ws; (void)ws_size;

  hipMemsetAsync(out, 0, sizeof(float), stream);
  dim3 grid(RGROUPS, NCHUNK, Bd);
  sobel_loss_kernel<<<grid, THREADS, 0, stream>>>(pred, targ, out);
}